// Round 2
// baseline (3629.321 us; speedup 1.0000x reference)
//
#include <hip/hip_runtime.h>

#define NN 100000   // nodes

// ---------------- CSR build ----------------

__global__ void count_kernel(const int* __restrict__ rows, int* __restrict__ cnt, int n) {
    int i = blockIdx.x * blockDim.x + threadIdx.x;
    if (i < n) atomicAdd(&cnt[rows[i]], 1);
}

// Single-block exclusive scan of cnt[NN] -> offs[NN+1]; also re-initializes
// cnt[] in-place as the atomic cursor array for the scatter pass.
__global__ __launch_bounds__(1024) void scan_kernel(int* __restrict__ cnt_pos,
                                                    int* __restrict__ offs) {
    __shared__ int sm[1024];
    __shared__ int carry_s;
    int tid = threadIdx.x;
    if (tid == 0) carry_s = 0;
    __syncthreads();
    for (int base = 0; base < NN; base += 4096) {
        int idx0 = base + tid * 4;
        int v[4]; int s = 0;
        #pragma unroll
        for (int j = 0; j < 4; ++j) {
            int i = idx0 + j;
            v[j] = (i < NN) ? cnt_pos[i] : 0;
            s += v[j];
        }
        sm[tid] = s;
        __syncthreads();
        for (int off = 1; off < 1024; off <<= 1) {
            int t = (tid >= off) ? sm[tid - off] : 0;
            __syncthreads();
            sm[tid] += t;
            __syncthreads();
        }
        int run = (tid ? sm[tid - 1] : 0) + carry_s;
        #pragma unroll
        for (int j = 0; j < 4; ++j) {
            int i = idx0 + j;
            if (i < NN) { offs[i] = run; cnt_pos[i] = run; run += v[j]; }
        }
        __syncthreads();
        if (tid == 1023) carry_s += sm[1023];
        __syncthreads();
    }
    if (tid == 0) offs[NN] = carry_s;
}

// Scatter edges into row-sorted order as packed (col, val) pairs.
__global__ void build_sorted(const int* __restrict__ rows, const int* __restrict__ cols,
                             const float* __restrict__ vals, int* __restrict__ pos,
                             int2* __restrict__ edges, int n) {
    int i = blockIdx.x * blockDim.x + threadIdx.x;
    if (i < n) {
        int p = atomicAdd(&pos[rows[i]], 1);
        edges[p] = make_int2(cols[i], __float_as_int(vals[i]));
    }
}

// ---------------- fp32 GEMM: C[M,N] = A[M,K] @ B[K,N] ----------------
// 64x64 tile, BK=16, 256 threads, 4x4 microtile. As padded to 68 floats/row:
// keeps 16B alignment (68*4=272=17*16) and spreads transpose-store banks 2-way.

template<int K, int N>
__global__ __launch_bounds__(256) void gemm_kernel(const float* __restrict__ A,
                                                   const float* __restrict__ B,
                                                   float* __restrict__ C) {
    __shared__ float As[16][68];
    __shared__ float Bs[16][64];
    const int tid = threadIdx.x;
    const int m0 = blockIdx.y * 64;
    const int n0 = blockIdx.x * 64;
    const int tx = tid & 15;        // n direction
    const int ty = tid >> 4;        // m direction
    const int la_m = tid >> 2;      // 0..63
    const int la_k = (tid & 3) << 2;
    const int lb_k = tid >> 4;      // 0..15
    const int lb_n = (tid & 15) << 2;
    float acc[4][4] = {};
    int am = m0 + la_m; if (am >= NN) am = NN - 1;   // clamp; store guarded
    const float* Arow = A + (size_t)am * K;

    for (int k0 = 0; k0 < K; k0 += 16) {
        float4 a = *(const float4*)(Arow + k0 + la_k);
        As[la_k + 0][la_m] = a.x;
        As[la_k + 1][la_m] = a.y;
        As[la_k + 2][la_m] = a.z;
        As[la_k + 3][la_m] = a.w;
        float4 b = make_float4(0.f, 0.f, 0.f, 0.f);
        if (n0 + lb_n < N) b = *(const float4*)(B + (size_t)(k0 + lb_k) * N + n0 + lb_n);
        *(float4*)&Bs[lb_k][lb_n] = b;
        __syncthreads();
        #pragma unroll
        for (int kk = 0; kk < 16; ++kk) {
            float4 a4 = *(const float4*)&As[kk][ty << 2];
            float4 b4 = *(const float4*)&Bs[kk][tx << 2];
            float av[4] = {a4.x, a4.y, a4.z, a4.w};
            float bv[4] = {b4.x, b4.y, b4.z, b4.w};
            #pragma unroll
            for (int i = 0; i < 4; ++i)
                #pragma unroll
                for (int j = 0; j < 4; ++j)
                    acc[i][j] = fmaf(av[i], bv[j], acc[i][j]);
        }
        __syncthreads();
    }
    #pragma unroll
    for (int i = 0; i < 4; ++i) {
        int m = m0 + (ty << 2) + i;
        if (m < NN) {
            int nbase = n0 + (tx << 2);
            float* Crow = C + (size_t)m * N + nbase;
            if (nbase + 3 < N) {
                *(float4*)Crow = make_float4(acc[i][0], acc[i][1], acc[i][2], acc[i][3]);
            } else {
                #pragma unroll
                for (int j = 0; j < 4; ++j)
                    if (nbase + j < N) Crow[j] = acc[i][j];
            }
        }
    }
}

// ---------------- SpMM, F=256: one block per destination row ----------------
// MODE 0: h[r] = relu(acc)            (layer 1)
// MODE 1: h[r] = relu(acc) + h[r]     (residual layers, safe in-place: block owns row)

template<int MODE>
__global__ __launch_bounds__(256) void spmm256_kernel(const int* __restrict__ offs,
                                                      const int2* __restrict__ edges,
                                                      const float* __restrict__ g,
                                                      float* __restrict__ h) {
    int r = blockIdx.x;
    int f = threadIdx.x;
    int e0 = offs[r], e1 = offs[r + 1];
    float acc = 0.f;
    for (int e = e0; e < e1; ++e) {
        int2 ed = edges[e];                          // wave-uniform 8B load
        acc = fmaf(__int_as_float(ed.y), g[(size_t)ed.x * 256 + f], acc);
    }
    size_t o = (size_t)r * 256 + f;
    float v = fmaxf(acc, 0.f);
    if (MODE == 1) v += h[o];
    h[o] = v;
}

// ---------------- SpMM, F=40 (final, no relu): one wave per row ----------------

__global__ __launch_bounds__(256) void spmm40_kernel(const int* __restrict__ offs,
                                                     const int2* __restrict__ edges,
                                                     const float* __restrict__ g,
                                                     float* __restrict__ out) {
    int r = blockIdx.x * 4 + (threadIdx.x >> 6);
    int f = threadIdx.x & 63;
    if (r >= NN || f >= 40) return;   // no barriers below: early-exit is safe
    int e0 = offs[r], e1 = offs[r + 1];
    float acc = 0.f;
    for (int e = e0; e < e1; ++e) {
        int2 ed = edges[e];
        acc = fmaf(__int_as_float(ed.y), g[(size_t)ed.x * 40 + f], acc);
    }
    out[(size_t)r * 40 + f] = acc;
}

// ---------------- launch ----------------

extern "C" void kernel_launch(void* const* d_in, const int* in_sizes, int n_in,
                              void* d_out, int out_size, void* d_ws, size_t ws_size,
                              hipStream_t stream) {
    const float* x     = (const float*)d_in[0];
    const int*   erows = (const int*)d_in[1];
    const int*   ecols = (const int*)d_in[2];
    const float* evals = (const float*)d_in[3];
    const float* W_in  = (const float*)d_in[4];
    const float* W_h1  = (const float*)d_in[5];
    const float* W_h2  = (const float*)d_in[6];
    const float* W_out = (const float*)d_in[7];
    float* out = (float*)d_out;
    const int ne = in_sizes[1];

    // workspace carve-out (~231 MB total)
    char* ws = (char*)d_ws;
    size_t woff = 0;
    auto alloc = [&](size_t bytes) -> void* {
        void* p = ws + woff;
        woff += (bytes + 255) & ~(size_t)255;
        return p;
    };
    int*   offs  = (int*)alloc((NN + 1) * sizeof(int));
    int*   pos   = (int*)alloc(NN * sizeof(int));          // counts, then cursors
    int2*  edges = (int2*)alloc((size_t)ne * sizeof(int2));
    float* g     = (float*)alloc((size_t)NN * 256 * sizeof(float)); // gemm out / gather src
    float* h     = (float*)alloc((size_t)NN * 256 * sizeof(float)); // hidden state

    // CSR build (graph identical across the 4 spmms; rebuilt each launch)
    hipMemsetAsync(pos, 0, NN * sizeof(int), stream);
    int nb = (ne + 255) / 256;
    count_kernel<<<nb, 256, 0, stream>>>(erows, pos, ne);
    scan_kernel<<<1, 1024, 0, stream>>>(pos, offs);
    build_sorted<<<nb, 256, 0, stream>>>(erows, ecols, evals, pos, edges, ne);

    dim3 gdim256(4, (NN + 63) / 64);   // N=256: 4 n-tiles
    dim3 gdim40 (1, (NN + 63) / 64);   // N=40 : 1 n-tile

    // layer 1: h = relu(spmm(x @ W_in))
    gemm_kernel<512, 256><<<gdim256, 256, 0, stream>>>(x, W_in, g);
    spmm256_kernel<0><<<NN, 256, 0, stream>>>(offs, edges, g, h);
    // layer 2: h = relu(spmm(h @ W_h1)) + h
    gemm_kernel<256, 256><<<gdim256, 256, 0, stream>>>(h, W_h1, g);
    spmm256_kernel<1><<<NN, 256, 0, stream>>>(offs, edges, g, h);
    // layer 3: h = relu(spmm(h @ W_h2)) + h
    gemm_kernel<256, 256><<<gdim256, 256, 0, stream>>>(h, W_h2, g);
    spmm256_kernel<1><<<NN, 256, 0, stream>>>(offs, edges, g, h);
    // output: logits = spmm(h @ W_out)
    gemm_kernel<256, 40><<<gdim40, 256, 0, stream>>>(h, W_out, g);  // g reused as [NN][40]
    spmm40_kernel<<<NN / 4, 256, 0, stream>>>(offs, edges, g, out);
}

// Round 6
// 1687.331 us; speedup vs baseline: 2.1509x; 2.1509x over previous
//
#include <hip/hip_runtime.h>
#include <hip/hip_bf16.h>

#define NN 100000   // nodes

typedef __attribute__((ext_vector_type(8))) short short8;
typedef __attribute__((ext_vector_type(4))) float f32x4;
typedef __attribute__((ext_vector_type(4))) unsigned short u16x4;

__device__ __forceinline__ float bf2f(unsigned short u) {
    return __uint_as_float((unsigned)u << 16);
}
__device__ __forceinline__ unsigned short f2bf(float f) {
    union { __hip_bfloat16 b; unsigned short u; } c;
    c.b = __float2bfloat16(f);
    return c.u;
}

// ---------------- CSR build ----------------

__global__ void count_kernel(const int* __restrict__ rows, int* __restrict__ cnt, int n) {
    int i = blockIdx.x * blockDim.x + threadIdx.x;
    if (i < n) atomicAdd(&cnt[rows[i]], 1);
}

// Single-block exclusive scan of cnt[NN] -> offs[NN+1]; also re-initializes
// cnt[] in-place as the atomic cursor array for the scatter pass.
__global__ __launch_bounds__(1024) void scan_kernel(int* __restrict__ cnt_pos,
                                                    int* __restrict__ offs) {
    __shared__ int sm[1024];
    __shared__ int carry_s;
    int tid = threadIdx.x;
    if (tid == 0) carry_s = 0;
    __syncthreads();
    for (int base = 0; base < NN; base += 4096) {
        int idx0 = base + tid * 4;
        int v[4]; int s = 0;
        #pragma unroll
        for (int j = 0; j < 4; ++j) {
            int i = idx0 + j;
            v[j] = (i < NN) ? cnt_pos[i] : 0;
            s += v[j];
        }
        sm[tid] = s;
        __syncthreads();
        for (int off = 1; off < 1024; off <<= 1) {
            int t = (tid >= off) ? sm[tid - off] : 0;
            __syncthreads();
            sm[tid] += t;
            __syncthreads();
        }
        int run = (tid ? sm[tid - 1] : 0) + carry_s;
        #pragma unroll
        for (int j = 0; j < 4; ++j) {
            int i = idx0 + j;
            if (i < NN) { offs[i] = run; cnt_pos[i] = run; run += v[j]; }
        }
        __syncthreads();
        if (tid == 1023) carry_s += sm[1023];
        __syncthreads();
    }
    if (tid == 0) offs[NN] = carry_s;
}

// Scatter edges into row-sorted order as packed (col, val) pairs.
__global__ void build_sorted(const int* __restrict__ rows, const int* __restrict__ cols,
                             const float* __restrict__ vals, int* __restrict__ pos,
                             int2* __restrict__ edges, int n) {
    int i = blockIdx.x * blockDim.x + threadIdx.x;
    if (i < n) {
        int p = atomicAdd(&pos[rows[i]], 1);
        edges[p] = make_int2(cols[i], __float_as_int(vals[i]));
    }
}

// ---------------- W transpose+convert: Wt[n][k] = bf16(W[k][n]) ----------------

__global__ void wt_kernel(const float* __restrict__ W, __hip_bfloat16* __restrict__ Wt,
                          int K, int N) {
    int i = blockIdx.x * blockDim.x + threadIdx.x;
    if (i < K * N) {
        int n = i / K, k = i - n * K;
        Wt[i] = __float2bfloat16(W[(size_t)k * N + n]);
    }
}

// ---------------- bf16 MFMA GEMM: C[M,N] = A[M,K] @ Bt[N,K]^T ----------------
// 128x128 tile, BK=32, 256 threads (4 waves, 2x2), each wave 64x64 out
// (4x4 frags of 16x16x32). LDS rows padded to 40 bf16 (80B: 16B-aligned,
// 2-way-max bank aliasing on frag reads = free).  [UNCHANGED from round 2]

template<int K, int N, bool A_FP32>
__global__ __launch_bounds__(256) void gemm_mfma(const void* __restrict__ Ap,
                                                 const __hip_bfloat16* __restrict__ Bt,
                                                 __hip_bfloat16* __restrict__ C) {
    __shared__ __hip_bfloat16 As[128][40];
    __shared__ __hip_bfloat16 Bs[128][40];
    const int tid  = threadIdx.x;
    const int m0   = blockIdx.y * 128;
    const int n0   = blockIdx.x * 128;
    const int lane = tid & 63;
    const int wave = tid >> 6;
    const int wr   = (wave >> 1) * 64;      // wave row offset in tile
    const int wc   = (wave & 1) * 64;       // wave col offset in tile
    const int srow = tid >> 1;              // staging row 0..127
    const int sk   = (tid & 1) * 16;        // staging k-offset (16 bf16)
    const int lm   = lane & 15;
    const int lk   = (lane >> 4) * 8;       // fragment k-offset

    f32x4 acc[4][4] = {};
    int am = m0 + srow; if (am >= NN) am = NN - 1;   // clamp; C-store guarded
    const int bn = n0 + srow;

    for (int k0 = 0; k0 < K; k0 += 32) {
        // ---- stage A tile [128][32] ----
        if (A_FP32) {
            const float* Ar = (const float*)Ap + (size_t)am * K + k0 + sk;
            float4 f0 = ((const float4*)Ar)[0];
            float4 f1 = ((const float4*)Ar)[1];
            float4 f2 = ((const float4*)Ar)[2];
            float4 f3 = ((const float4*)Ar)[3];
            union { short8 v; __hip_bfloat16 e[8]; } u0, u1;
            u0.e[0] = __float2bfloat16(f0.x); u0.e[1] = __float2bfloat16(f0.y);
            u0.e[2] = __float2bfloat16(f0.z); u0.e[3] = __float2bfloat16(f0.w);
            u0.e[4] = __float2bfloat16(f1.x); u0.e[5] = __float2bfloat16(f1.y);
            u0.e[6] = __float2bfloat16(f1.z); u0.e[7] = __float2bfloat16(f1.w);
            u1.e[0] = __float2bfloat16(f2.x); u1.e[1] = __float2bfloat16(f2.y);
            u1.e[2] = __float2bfloat16(f2.z); u1.e[3] = __float2bfloat16(f2.w);
            u1.e[4] = __float2bfloat16(f3.x); u1.e[5] = __float2bfloat16(f3.y);
            u1.e[6] = __float2bfloat16(f3.z); u1.e[7] = __float2bfloat16(f3.w);
            *(short8*)&As[srow][sk]     = u0.v;
            *(short8*)&As[srow][sk + 8] = u1.v;
        } else {
            const __hip_bfloat16* Ar = (const __hip_bfloat16*)Ap + (size_t)am * K + k0 + sk;
            *(short8*)&As[srow][sk]     = ((const short8*)Ar)[0];
            *(short8*)&As[srow][sk + 8] = ((const short8*)Ar)[1];
        }
        // ---- stage B tile [128][32] from Bt[N][K] ----
        if (bn < N) {
            const __hip_bfloat16* Br = Bt + (size_t)bn * K + k0 + sk;
            *(short8*)&Bs[srow][sk]     = ((const short8*)Br)[0];
            *(short8*)&Bs[srow][sk + 8] = ((const short8*)Br)[1];
        } else {
            short8 z = {};
            *(short8*)&Bs[srow][sk]     = z;
            *(short8*)&Bs[srow][sk + 8] = z;
        }
        __syncthreads();

        short8 af[4], bfr[4];
        #pragma unroll
        for (int q = 0; q < 4; ++q)
            af[q] = *(const short8*)&As[wr + q * 16 + lm][lk];
        #pragma unroll
        for (int r = 0; r < 4; ++r)
            bfr[r] = *(const short8*)&Bs[wc + r * 16 + lm][lk];
        #pragma unroll
        for (int q = 0; q < 4; ++q)
            #pragma unroll
            for (int r = 0; r < 4; ++r)
                acc[q][r] = __builtin_amdgcn_mfma_f32_16x16x32_bf16(af[q], bfr[r], acc[q][r], 0, 0, 0);
        __syncthreads();
    }

    // ---- epilogue: C/D layout col=lane&15, row=(lane>>4)*4+j ----
    #pragma unroll
    for (int q = 0; q < 4; ++q) {
        #pragma unroll
        for (int r = 0; r < 4; ++r) {
            #pragma unroll
            for (int j = 0; j < 4; ++j) {
                int m = m0 + wr + q * 16 + (lane >> 4) * 4 + j;
                int n = n0 + wc + r * 16 + lm;
                if (m < NN && n < N)
                    C[(size_t)m * N + n] = __float2bfloat16(acc[q][r][j]);
            }
        }
    }
}

// ---------------- SpMM, F=256: wave-per-row, batched edges ----------------
// Wave loads 64 edges coalesced, broadcasts (col,val) via v_readlane, gathers
// u16x4 (8B/lane, 512B/wave/edge). 2x-unrolled inner loop -> >=2 gathers in
// flight per wave. MODE 0: h=relu(acc); MODE 1: h=relu(acc)+h (wave owns row).

template<int MODE>
__global__ __launch_bounds__(256) void spmm256_kernel(const int* __restrict__ offs,
                                                      const int2* __restrict__ edges,
                                                      const __hip_bfloat16* __restrict__ g,
                                                      __hip_bfloat16* __restrict__ h) {
    const int wid  = threadIdx.x >> 6;
    const int lane = threadIdx.x & 63;
    const int r = blockIdx.x * 4 + wid;
    if (r >= NN) return;
    const int e0 = offs[r], e1 = offs[r + 1];
    const unsigned short* gp = (const unsigned short*)g;
    float a0 = 0.f, a1 = 0.f, a2 = 0.f, a3 = 0.f;

    for (int base = e0; base < e1; base += 64) {
        int ei = base + lane;
        int2 my = (ei < e1) ? edges[ei] : make_int2(0, 0);
        int cnt = min(64, e1 - base);
        int j = 0;
        for (; j + 1 < cnt; j += 2) {
            int   c0 = __builtin_amdgcn_readlane(my.x, j);
            float v0 = __uint_as_float((unsigned)__builtin_amdgcn_readlane(my.y, j));
            int   c1 = __builtin_amdgcn_readlane(my.x, j + 1);
            float v1 = __uint_as_float((unsigned)__builtin_amdgcn_readlane(my.y, j + 1));
            u16x4 g0 = *(const u16x4*)(gp + (size_t)c0 * 256 + lane * 4);
            u16x4 g1 = *(const u16x4*)(gp + (size_t)c1 * 256 + lane * 4);
            a0 = fmaf(v0, bf2f(g0.x), a0);
            a1 = fmaf(v0, bf2f(g0.y), a1);
            a2 = fmaf(v0, bf2f(g0.z), a2);
            a3 = fmaf(v0, bf2f(g0.w), a3);
            a0 = fmaf(v1, bf2f(g1.x), a0);
            a1 = fmaf(v1, bf2f(g1.y), a1);
            a2 = fmaf(v1, bf2f(g1.z), a2);
            a3 = fmaf(v1, bf2f(g1.w), a3);
        }
        if (j < cnt) {
            int   c0 = __builtin_amdgcn_readlane(my.x, j);
            float v0 = __uint_as_float((unsigned)__builtin_amdgcn_readlane(my.y, j));
            u16x4 g0 = *(const u16x4*)(gp + (size_t)c0 * 256 + lane * 4);
            a0 = fmaf(v0, bf2f(g0.x), a0);
            a1 = fmaf(v0, bf2f(g0.y), a1);
            a2 = fmaf(v0, bf2f(g0.z), a2);
            a3 = fmaf(v0, bf2f(g0.w), a3);
        }
    }

    a0 = fmaxf(a0, 0.f); a1 = fmaxf(a1, 0.f);
    a2 = fmaxf(a2, 0.f); a3 = fmaxf(a3, 0.f);
    unsigned short* hp = (unsigned short*)h + (size_t)r * 256 + lane * 4;
    if (MODE == 1) {
        u16x4 hv = *(const u16x4*)hp;
        a0 += bf2f(hv.x); a1 += bf2f(hv.y);
        a2 += bf2f(hv.z); a3 += bf2f(hv.w);
    }
    u16x4 ov;
    ov.x = f2bf(a0); ov.y = f2bf(a1); ov.z = f2bf(a2); ov.w = f2bf(a3);
    *(u16x4*)hp = ov;
}

// ---------------- SpMM, F=40 (final, no relu, fp32 out): wave-per-row ----------------
// Same edge batching; lanes 0..39 carry one feature each (lanes 40..63 still
// participate in the coalesced edge load for readlane).

__global__ __launch_bounds__(256) void spmm40_kernel(const int* __restrict__ offs,
                                                     const int2* __restrict__ edges,
                                                     const __hip_bfloat16* __restrict__ g,
                                                     float* __restrict__ out) {
    const int wid  = threadIdx.x >> 6;
    const int lane = threadIdx.x & 63;
    const int r = blockIdx.x * 4 + wid;
    if (r >= NN) return;
    const int e0 = offs[r], e1 = offs[r + 1];
    const unsigned short* gp = (const unsigned short*)g;
    float acc = 0.f;

    for (int base = e0; base < e1; base += 64) {
        int ei = base + lane;
        int2 my = (ei < e1) ? edges[ei] : make_int2(0, 0);
        int cnt = min(64, e1 - base);
        int j = 0;
        for (; j + 1 < cnt; j += 2) {
            int   c0 = __builtin_amdgcn_readlane(my.x, j);
            float v0 = __uint_as_float((unsigned)__builtin_amdgcn_readlane(my.y, j));
            int   c1 = __builtin_amdgcn_readlane(my.x, j + 1);
            float v1 = __uint_as_float((unsigned)__builtin_amdgcn_readlane(my.y, j + 1));
            if (lane < 40) {
                unsigned short u0 = gp[(size_t)c0 * 40 + lane];
                unsigned short u1 = gp[(size_t)c1 * 40 + lane];
                acc = fmaf(v0, bf2f(u0), acc);
                acc = fmaf(v1, bf2f(u1), acc);
            }
        }
        if (j < cnt) {
            int   c0 = __builtin_amdgcn_readlane(my.x, j);
            float v0 = __uint_as_float((unsigned)__builtin_amdgcn_readlane(my.y, j));
            if (lane < 40) {
                unsigned short u0 = gp[(size_t)c0 * 40 + lane];
                acc = fmaf(v0, bf2f(u0), acc);
            }
        }
    }
    if (lane < 40) out[(size_t)r * 40 + lane] = acc;
}

// ---------------- launch ----------------

extern "C" void kernel_launch(void* const* d_in, const int* in_sizes, int n_in,
                              void* d_out, int out_size, void* d_ws, size_t ws_size,
                              hipStream_t stream) {
    const float* x     = (const float*)d_in[0];
    const int*   erows = (const int*)d_in[1];
    const int*   ecols = (const int*)d_in[2];
    const float* evals = (const float*)d_in[3];
    const float* W_in  = (const float*)d_in[4];
    const float* W_h1  = (const float*)d_in[5];
    const float* W_h2  = (const float*)d_in[6];
    const float* W_out = (const float*)d_in[7];
    float* out = (float*)d_out;
    const int ne = in_sizes[1];

    // workspace carve-out (~130 MB total)
    char* ws = (char*)d_ws;
    size_t woff = 0;
    auto alloc = [&](size_t bytes) -> void* {
        void* p = ws + woff;
        woff += (bytes + 255) & ~(size_t)255;
        return p;
    };
    int*  offs  = (int*)alloc((NN + 1) * sizeof(int));
    int*  pos   = (int*)alloc(NN * sizeof(int));           // counts, then cursors
    int2* edges = (int2*)alloc((size_t)ne * sizeof(int2));
    __hip_bfloat16* g  = (__hip_bfloat16*)alloc((size_t)NN * 256 * 2);  // gemm out / gather src
    __hip_bfloat16* h  = (__hip_bfloat16*)alloc((size_t)NN * 256 * 2);  // hidden state
    __hip_bfloat16* Wt_in  = (__hip_bfloat16*)alloc(256 * 512 * 2);     // [N][K]
    __hip_bfloat16* Wt_h1  = (__hip_bfloat16*)alloc(256 * 256 * 2);
    __hip_bfloat16* Wt_h2  = (__hip_bfloat16*)alloc(256 * 256 * 2);
    __hip_bfloat16* Wt_out = (__hip_bfloat16*)alloc(40 * 256 * 2);

    // CSR build (graph identical across the 4 spmms; rebuilt each launch)
    hipMemsetAsync(pos, 0, NN * sizeof(int), stream);
    int nb = (ne + 255) / 256;
    count_kernel<<<nb, 256, 0, stream>>>(erows, pos, ne);
    scan_kernel<<<1, 1024, 0, stream>>>(pos, offs);
    build_sorted<<<nb, 256, 0, stream>>>(erows, ecols, evals, pos, edges, ne);

    // weight transposes (tiny)
    wt_kernel<<<(512 * 256 + 255) / 256, 256, 0, stream>>>(W_in,  Wt_in,  512, 256);
    wt_kernel<<<(256 * 256 + 255) / 256, 256, 0, stream>>>(W_h1,  Wt_h1,  256, 256);
    wt_kernel<<<(256 * 256 + 255) / 256, 256, 0, stream>>>(W_h2,  Wt_h2,  256, 256);
    wt_kernel<<<(256 * 40  + 255) / 256, 256, 0, stream>>>(W_out, Wt_out, 256, 40);

    const int mt = (NN + 127) / 128;           // 782 m-tiles
    dim3 g256(2, mt), g40(1, mt);
    const int sb = (NN + 3) / 4;               // spmm blocks (4 rows per block)

    // layer 1: h = relu(spmm(x @ W_in))
    gemm_mfma<512, 256, true ><<<g256, 256, 0, stream>>>(x, Wt_in, g);
    spmm256_kernel<0><<<sb, 256, 0, stream>>>(offs, edges, g, h);
    // layer 2: h = relu(spmm(h @ W_h1)) + h
    gemm_mfma<256, 256, false><<<g256, 256, 0, stream>>>(h, Wt_h1, g);
    spmm256_kernel<1><<<sb, 256, 0, stream>>>(offs, edges, g, h);
    // layer 3: h = relu(spmm(h @ W_h2)) + h
    gemm_mfma<256, 256, false><<<g256, 256, 0, stream>>>(h, Wt_h2, g);
    spmm256_kernel<1><<<sb, 256, 0, stream>>>(offs, edges, g, h);
    // output: logits = spmm(h @ W_out)
    gemm_mfma<256, 40, false><<<g40, 256, 0, stream>>>(h, Wt_out, g);  // g as [NN][40]
    spmm40_kernel<<<sb, 256, 0, stream>>>(offs, edges, g, out);
}

// Round 9
// 1514.054 us; speedup vs baseline: 2.3971x; 1.1144x over previous
//
#include <hip/hip_runtime.h>
#include <hip/hip_bf16.h>
#include <hip/hip_fp16.h>

#define NN 100000          // nodes
#define NB 98              // scan blocks: ceil(NN/1024)
#define NSLICE 4
#define SLICE_ROWS 25000   // NN / NSLICE

typedef __attribute__((ext_vector_type(8))) short short8;
typedef __attribute__((ext_vector_type(4))) float f32x4;
typedef __attribute__((ext_vector_type(4))) unsigned short u16x4;

__device__ __forceinline__ float bf2f(unsigned short u) {
    return __uint_as_float((unsigned)u << 16);
}
__device__ __forceinline__ unsigned short f2bf(float f) {
    union { __hip_bfloat16 b; unsigned short u; } c;
    c.b = __float2bfloat16(f);
    return c.u;
}
// packed edge: bits[16:0] = col, bits[30:17] = fp16 bits of val (val in [0,1) -> <2^14)
__device__ __forceinline__ int   pcol(unsigned p) { return (int)(p & 0x1FFFFu); }
__device__ __forceinline__ float pval(unsigned p) {
    return __half2float(__ushort_as_half((unsigned short)(p >> 17)));
}

// ---------------- CSR build ----------------

__global__ void count_kernel(const int* __restrict__ rows, int* __restrict__ cnt, int n) {
    int i = blockIdx.x * blockDim.x + threadIdx.x;
    if (i < n) atomicAdd(&cnt[rows[i]], 1);
}

// scan1: per-1024-chunk sums
__global__ __launch_bounds__(256) void scan1(const int* __restrict__ cnt, int* __restrict__ bsums) {
    __shared__ int sm[256];
    int b = blockIdx.x, t = threadIdx.x;
    int base = b * 1024 + t * 4;
    int s = 0;
    #pragma unroll
    for (int j = 0; j < 4; ++j) { int i = base + j; if (i < NN) s += cnt[i]; }
    sm[t] = s; __syncthreads();
    for (int off = 128; off > 0; off >>= 1) {
        if (t < off) sm[t] += sm[t + off];
        __syncthreads();
    }
    if (t == 0) bsums[b] = sm[0];
}

// scan2: exclusive scan of the NB chunk sums (in place)
__global__ __launch_bounds__(128) void scan2(int* __restrict__ bsums) {
    __shared__ int sm[128];
    int t = threadIdx.x;
    int v = (t < NB) ? bsums[t] : 0;
    sm[t] = v; __syncthreads();
    for (int off = 1; off < 128; off <<= 1) {
        int u = (t >= off) ? sm[t - off] : 0;
        __syncthreads(); sm[t] += u; __syncthreads();
    }
    if (t < NB) bsums[t] = sm[t] - v;
}

// scan3: local exclusive scan + chunk base -> offs[] and cursor pos[]
__global__ __launch_bounds__(256) void scan3(const int* __restrict__ cnt, const int* __restrict__ bsums,
                                             int* __restrict__ offs, int* __restrict__ pos) {
    __shared__ int sm[256];
    int b = blockIdx.x, t = threadIdx.x;
    int base = b * 1024 + t * 4;
    int v[4]; int s = 0;
    #pragma unroll
    for (int j = 0; j < 4; ++j) { int i = base + j; v[j] = (i < NN) ? cnt[i] : 0; s += v[j]; }
    sm[t] = s; __syncthreads();
    for (int off = 1; off < 256; off <<= 1) {
        int u = (t >= off) ? sm[t - off] : 0;
        __syncthreads(); sm[t] += u; __syncthreads();
    }
    int run = bsums[b] + (t ? sm[t - 1] : 0);
    #pragma unroll
    for (int j = 0; j < 4; ++j) {
        int i = base + j;
        if (i < NN) {
            offs[i] = run; pos[i] = run; run += v[j];
            if (i == NN - 1) offs[NN] = run;
        }
    }
}

// Scatter edges (packed 4B) into row-sorted order. grid.y = slice of 25000 rows:
// slices dispatch roughly in order -> active dest region ~3.2MB -> L2 coalesces
// the random 4B writes into full lines before writeback (perf heuristic only).
__global__ void build_sorted(const int* __restrict__ rows, const int* __restrict__ cols,
                             const float* __restrict__ vals, int* __restrict__ pos,
                             unsigned* __restrict__ edges, int n) {
    int i = blockIdx.x * blockDim.x + threadIdx.x;
    int lo = blockIdx.y * SLICE_ROWS;
    if (i < n) {
        int r = rows[i];
        if (r >= lo && r < lo + SLICE_ROWS) {
            int p = atomicAdd(&pos[r], 1);
            unsigned hb = (unsigned)__half_as_ushort(__float2half(vals[i]));
            edges[p] = (hb << 17) | (unsigned)cols[i];
        }
    }
}

// ---------------- W transpose+convert: Wt[n][k] = bf16(W[k][n]) ----------------

__global__ void wt_kernel(const float* __restrict__ W, __hip_bfloat16* __restrict__ Wt,
                          int K, int N) {
    int i = blockIdx.x * blockDim.x + threadIdx.x;
    if (i < K * N) {
        int n = i / K, k = i - n * K;
        Wt[i] = __float2bfloat16(W[(size_t)k * N + n]);
    }
}

// ---------------- bf16 MFMA GEMM: C[M,N] = A[M,K] @ Bt[N,K]^T ----------------
// [UNCHANGED — byte-identical for clean attribution]

template<int K, int N, bool A_FP32>
__global__ __launch_bounds__(256) void gemm_mfma(const void* __restrict__ Ap,
                                                 const __hip_bfloat16* __restrict__ Bt,
                                                 __hip_bfloat16* __restrict__ C) {
    __shared__ __hip_bfloat16 As[128][40];
    __shared__ __hip_bfloat16 Bs[128][40];
    const int tid  = threadIdx.x;
    const int m0   = blockIdx.y * 128;
    const int n0   = blockIdx.x * 128;
    const int lane = tid & 63;
    const int wave = tid >> 6;
    const int wr   = (wave >> 1) * 64;      // wave row offset in tile
    const int wc   = (wave & 1) * 64;       // wave col offset in tile
    const int srow = tid >> 1;              // staging row 0..127
    const int sk   = (tid & 1) * 16;        // staging k-offset (16 bf16)
    const int lm   = lane & 15;
    const int lk   = (lane >> 4) * 8;       // fragment k-offset

    f32x4 acc[4][4] = {};
    int am = m0 + srow; if (am >= NN) am = NN - 1;   // clamp; C-store guarded
    const int bn = n0 + srow;

    for (int k0 = 0; k0 < K; k0 += 32) {
        // ---- stage A tile [128][32] ----
        if (A_FP32) {
            const float* Ar = (const float*)Ap + (size_t)am * K + k0 + sk;
            float4 f0 = ((const float4*)Ar)[0];
            float4 f1 = ((const float4*)Ar)[1];
            float4 f2 = ((const float4*)Ar)[2];
            float4 f3 = ((const float4*)Ar)[3];
            union { short8 v; __hip_bfloat16 e[8]; } u0, u1;
            u0.e[0] = __float2bfloat16(f0.x); u0.e[1] = __float2bfloat16(f0.y);
            u0.e[2] = __float2bfloat16(f0.z); u0.e[3] = __float2bfloat16(f0.w);
            u0.e[4] = __float2bfloat16(f1.x); u0.e[5] = __float2bfloat16(f1.y);
            u0.e[6] = __float2bfloat16(f1.z); u0.e[7] = __float2bfloat16(f1.w);
            u1.e[0] = __float2bfloat16(f2.x); u1.e[1] = __float2bfloat16(f2.y);
            u1.e[2] = __float2bfloat16(f2.z); u1.e[3] = __float2bfloat16(f2.w);
            u1.e[4] = __float2bfloat16(f3.x); u1.e[5] = __float2bfloat16(f3.y);
            u1.e[6] = __float2bfloat16(f3.z); u1.e[7] = __float2bfloat16(f3.w);
            *(short8*)&As[srow][sk]     = u0.v;
            *(short8*)&As[srow][sk + 8] = u1.v;
        } else {
            const __hip_bfloat16* Ar = (const __hip_bfloat16*)Ap + (size_t)am * K + k0 + sk;
            *(short8*)&As[srow][sk]     = ((const short8*)Ar)[0];
            *(short8*)&As[srow][sk + 8] = ((const short8*)Ar)[1];
        }
        // ---- stage B tile [128][32] from Bt[N][K] ----
        if (bn < N) {
            const __hip_bfloat16* Br = Bt + (size_t)bn * K + k0 + sk;
            *(short8*)&Bs[srow][sk]     = ((const short8*)Br)[0];
            *(short8*)&Bs[srow][sk + 8] = ((const short8*)Br)[1];
        } else {
            short8 z = {};
            *(short8*)&Bs[srow][sk]     = z;
            *(short8*)&Bs[srow][sk + 8] = z;
        }
        __syncthreads();

        short8 af[4], bfr[4];
        #pragma unroll
        for (int q = 0; q < 4; ++q)
            af[q] = *(const short8*)&As[wr + q * 16 + lm][lk];
        #pragma unroll
        for (int r = 0; r < 4; ++r)
            bfr[r] = *(const short8*)&Bs[wc + r * 16 + lm][lk];
        #pragma unroll
        for (int q = 0; q < 4; ++q)
            #pragma unroll
            for (int r = 0; r < 4; ++r)
                acc[q][r] = __builtin_amdgcn_mfma_f32_16x16x32_bf16(af[q], bfr[r], acc[q][r], 0, 0, 0);
        __syncthreads();
    }

    // ---- epilogue: C/D layout col=lane&15, row=(lane>>4)*4+j ----
    #pragma unroll
    for (int q = 0; q < 4; ++q) {
        #pragma unroll
        for (int r = 0; r < 4; ++r) {
            #pragma unroll
            for (int j = 0; j < 4; ++j) {
                int m = m0 + wr + q * 16 + (lane >> 4) * 4 + j;
                int n = n0 + wc + r * 16 + lm;
                if (m < NN && n < N)
                    C[(size_t)m * N + n] = __float2bfloat16(acc[q][r][j]);
            }
        }
    }
}

// ---------------- SpMM, F=256: wave-per-row, batched packed edges ----------------
// Wave loads 64 packed edges coalesced, broadcasts via one readlane each,
// gathers u16x4 (8B/lane). Unroll-4 -> 4 gathers in flight per wave.

template<int MODE>
__global__ __launch_bounds__(256) void spmm256_kernel(const int* __restrict__ offs,
                                                      const unsigned* __restrict__ edges,
                                                      const __hip_bfloat16* __restrict__ g,
                                                      __hip_bfloat16* __restrict__ h) {
    const int wid  = threadIdx.x >> 6;
    const int lane = threadIdx.x & 63;
    const int r = blockIdx.x * 4 + wid;
    if (r >= NN) return;
    const int e0 = offs[r], e1 = offs[r + 1];
    const unsigned short* gp = (const unsigned short*)g;
    float a0 = 0.f, a1 = 0.f, a2 = 0.f, a3 = 0.f;

    for (int base = e0; base < e1; base += 64) {
        int ei = base + lane;
        unsigned my = (ei < e1) ? edges[ei] : 0u;
        int cnt = min(64, e1 - base);
        int j = 0;
        for (; j + 3 < cnt; j += 4) {
            unsigned p0 = (unsigned)__builtin_amdgcn_readlane((int)my, j);
            unsigned p1 = (unsigned)__builtin_amdgcn_readlane((int)my, j + 1);
            unsigned p2 = (unsigned)__builtin_amdgcn_readlane((int)my, j + 2);
            unsigned p3 = (unsigned)__builtin_amdgcn_readlane((int)my, j + 3);
            u16x4 g0 = *(const u16x4*)(gp + (size_t)pcol(p0) * 256 + lane * 4);
            u16x4 g1 = *(const u16x4*)(gp + (size_t)pcol(p1) * 256 + lane * 4);
            u16x4 g2 = *(const u16x4*)(gp + (size_t)pcol(p2) * 256 + lane * 4);
            u16x4 g3 = *(const u16x4*)(gp + (size_t)pcol(p3) * 256 + lane * 4);
            float v0 = pval(p0), v1 = pval(p1), v2 = pval(p2), v3 = pval(p3);
            a0 = fmaf(v0, bf2f(g0.x), a0); a1 = fmaf(v0, bf2f(g0.y), a1);
            a2 = fmaf(v0, bf2f(g0.z), a2); a3 = fmaf(v0, bf2f(g0.w), a3);
            a0 = fmaf(v1, bf2f(g1.x), a0); a1 = fmaf(v1, bf2f(g1.y), a1);
            a2 = fmaf(v1, bf2f(g1.z), a2); a3 = fmaf(v1, bf2f(g1.w), a3);
            a0 = fmaf(v2, bf2f(g2.x), a0); a1 = fmaf(v2, bf2f(g2.y), a1);
            a2 = fmaf(v2, bf2f(g2.z), a2); a3 = fmaf(v2, bf2f(g2.w), a3);
            a0 = fmaf(v3, bf2f(g3.x), a0); a1 = fmaf(v3, bf2f(g3.y), a1);
            a2 = fmaf(v3, bf2f(g3.z), a2); a3 = fmaf(v3, bf2f(g3.w), a3);
        }
        for (; j < cnt; ++j) {
            unsigned p0 = (unsigned)__builtin_amdgcn_readlane((int)my, j);
            u16x4 g0 = *(const u16x4*)(gp + (size_t)pcol(p0) * 256 + lane * 4);
            float v0 = pval(p0);
            a0 = fmaf(v0, bf2f(g0.x), a0); a1 = fmaf(v0, bf2f(g0.y), a1);
            a2 = fmaf(v0, bf2f(g0.z), a2); a3 = fmaf(v0, bf2f(g0.w), a3);
        }
    }

    a0 = fmaxf(a0, 0.f); a1 = fmaxf(a1, 0.f);
    a2 = fmaxf(a2, 0.f); a3 = fmaxf(a3, 0.f);
    unsigned short* hp = (unsigned short*)h + (size_t)r * 256 + lane * 4;
    if (MODE == 1) {
        u16x4 hv = *(const u16x4*)hp;
        a0 += bf2f(hv.x); a1 += bf2f(hv.y);
        a2 += bf2f(hv.z); a3 += bf2f(hv.w);
    }
    u16x4 ov;
    ov.x = f2bf(a0); ov.y = f2bf(a1); ov.z = f2bf(a2); ov.w = f2bf(a3);
    *(u16x4*)hp = ov;
}

// ---------------- SpMM, F=40 (final, no relu, fp32 out): wave-per-row ----------------

__global__ __launch_bounds__(256) void spmm40_kernel(const int* __restrict__ offs,
                                                     const unsigned* __restrict__ edges,
                                                     const __hip_bfloat16* __restrict__ g,
                                                     float* __restrict__ out) {
    const int wid  = threadIdx.x >> 6;
    const int lane = threadIdx.x & 63;
    const int r = blockIdx.x * 4 + (threadIdx.x >> 6);
    if (r >= NN) return;
    const int e0 = offs[r], e1 = offs[r + 1];
    const unsigned short* gp = (const unsigned short*)g;
    float acc = 0.f;

    for (int base = e0; base < e1; base += 64) {
        int ei = base + lane;
        unsigned my = (ei < e1) ? edges[ei] : 0u;
        int cnt = min(64, e1 - base);
        int j = 0;
        for (; j + 1 < cnt; j += 2) {
            unsigned p0 = (unsigned)__builtin_amdgcn_readlane((int)my, j);
            unsigned p1 = (unsigned)__builtin_amdgcn_readlane((int)my, j + 1);
            if (lane < 40) {
                unsigned short u0 = gp[(size_t)pcol(p0) * 40 + lane];
                unsigned short u1 = gp[(size_t)pcol(p1) * 40 + lane];
                acc = fmaf(pval(p0), bf2f(u0), acc);
                acc = fmaf(pval(p1), bf2f(u1), acc);
            }
        }
        if (j < cnt) {
            unsigned p0 = (unsigned)__builtin_amdgcn_readlane((int)my, j);
            if (lane < 40) {
                unsigned short u0 = gp[(size_t)pcol(p0) * 40 + lane];
                acc = fmaf(pval(p0), bf2f(u0), acc);
            }
        }
    }
    if (lane < 40) out[(size_t)r * 40 + lane] = acc;
}

// ---------------- launch ----------------

extern "C" void kernel_launch(void* const* d_in, const int* in_sizes, int n_in,
                              void* d_out, int out_size, void* d_ws, size_t ws_size,
                              hipStream_t stream) {
    const float* x     = (const float*)d_in[0];
    const int*   erows = (const int*)d_in[1];
    const int*   ecols = (const int*)d_in[2];
    const float* evals = (const float*)d_in[3];
    const float* W_in  = (const float*)d_in[4];
    const float* W_h1  = (const float*)d_in[5];
    const float* W_h2  = (const float*)d_in[6];
    const float* W_out = (const float*)d_in[7];
    float* out = (float*)d_out;
    const int ne = in_sizes[1];

    // workspace carve-out (~118 MB total)
    char* ws = (char*)d_ws;
    size_t woff = 0;
    auto alloc = [&](size_t bytes) -> void* {
        void* p = ws + woff;
        woff += (bytes + 255) & ~(size_t)255;
        return p;
    };
    int*      cnt   = (int*)alloc(NN * sizeof(int));
    int*      pos   = (int*)alloc(NN * sizeof(int));
    int*      bsums = (int*)alloc(128 * sizeof(int));
    int*      offs  = (int*)alloc((NN + 1) * sizeof(int));
    unsigned* edges = (unsigned*)alloc((size_t)ne * sizeof(unsigned));
    __hip_bfloat16* g  = (__hip_bfloat16*)alloc((size_t)NN * 256 * 2);  // gemm out / gather src
    __hip_bfloat16* h  = (__hip_bfloat16*)alloc((size_t)NN * 256 * 2);  // hidden state
    __hip_bfloat16* Wt_in  = (__hip_bfloat16*)alloc(256 * 512 * 2);     // [N][K]
    __hip_bfloat16* Wt_h1  = (__hip_bfloat16*)alloc(256 * 256 * 2);
    __hip_bfloat16* Wt_h2  = (__hip_bfloat16*)alloc(256 * 256 * 2);
    __hip_bfloat16* Wt_out = (__hip_bfloat16*)alloc(40 * 256 * 2);

    // CSR build (rebuilt each launch; graph shared by all 4 spmms)
    hipMemsetAsync(cnt, 0, NN * sizeof(int), stream);
    int nb = (ne + 255) / 256;
    count_kernel<<<nb, 256, 0, stream>>>(erows, cnt, ne);
    scan1<<<NB, 256, 0, stream>>>(cnt, bsums);
    scan2<<<1, 128, 0, stream>>>(bsums);
    scan3<<<NB, 256, 0, stream>>>(cnt, bsums, offs, pos);
    build_sorted<<<dim3(nb, NSLICE), 256, 0, stream>>>(erows, ecols, evals, pos, edges, ne);

    // weight transposes (tiny)
    wt_kernel<<<(512 * 256 + 255) / 256, 256, 0, stream>>>(W_in,  Wt_in,  512, 256);
    wt_kernel<<<(256 * 256 + 255) / 256, 256, 0, stream>>>(W_h1,  Wt_h1,  256, 256);
    wt_kernel<<<(256 * 256 + 255) / 256, 256, 0, stream>>>(W_h2,  Wt_h2,  256, 256);
    wt_kernel<<<(256 * 40  + 255) / 256, 256, 0, stream>>>(W_out, Wt_out, 256, 40);

    const int mt = (NN + 127) / 128;           // 782 m-tiles
    dim3 g256(2, mt), g40(1, mt);
    const int sb = (NN + 3) / 4;               // spmm blocks (4 rows per block)

    // layer 1: h = relu(spmm(x @ W_in))
    gemm_mfma<512, 256, true ><<<g256, 256, 0, stream>>>(x, Wt_in, g);
    spmm256_kernel<0><<<sb, 256, 0, stream>>>(offs, edges, g, h);
    // layer 2: h = relu(spmm(h @ W_h1)) + h
    gemm_mfma<256, 256, false><<<g256, 256, 0, stream>>>(h, Wt_h1, g);
    spmm256_kernel<1><<<sb, 256, 0, stream>>>(offs, edges, g, h);
    // layer 3: h = relu(spmm(h @ W_h2)) + h
    gemm_mfma<256, 256, false><<<g256, 256, 0, stream>>>(h, Wt_h2, g);
    spmm256_kernel<1><<<sb, 256, 0, stream>>>(offs, edges, g, h);
    // output: logits = spmm(h @ W_out)
    gemm_mfma<256, 40, false><<<g40, 256, 0, stream>>>(h, Wt_out, g);  // g as [NN][40]
    spmm40_kernel<<<sb, 256, 0, stream>>>(offs, edges, g, out);
}

// Round 10
// 1481.744 us; speedup vs baseline: 2.4494x; 1.0218x over previous
//
#include <hip/hip_runtime.h>
#include <hip/hip_bf16.h>
#include <hip/hip_fp16.h>

#define NN 100000          // nodes
#define NB 98              // scan blocks: ceil(NN/1024)
#define NSLICE 4
#define SLICE_ROWS 25000   // NN / NSLICE

typedef __attribute__((ext_vector_type(8))) short short8;
typedef __attribute__((ext_vector_type(4))) float f32x4;
typedef __attribute__((ext_vector_type(4))) unsigned short u16x4;

__device__ __forceinline__ float bf2f(unsigned short u) {
    return __uint_as_float((unsigned)u << 16);
}
__device__ __forceinline__ unsigned short f2bf(float f) {
    union { __hip_bfloat16 b; unsigned short u; } c;
    c.b = __float2bfloat16(f);
    return c.u;
}
// packed edge: bits[16:0] = col, bits[30:17] = fp16 bits of val (val in [0,1) -> <2^14)
__device__ __forceinline__ int   pcol(unsigned p) { return (int)(p & 0x1FFFFu); }
__device__ __forceinline__ float pval(unsigned p) {
    return __half2float(__ushort_as_half((unsigned short)(p >> 17)));
}

// ---------------- CSR build ----------------

__global__ void count_kernel(const int* __restrict__ rows, int* __restrict__ cnt, int n) {
    int i = blockIdx.x * blockDim.x + threadIdx.x;
    if (i < n) atomicAdd(&cnt[rows[i]], 1);
}

// scan1: per-1024-chunk sums
__global__ __launch_bounds__(256) void scan1(const int* __restrict__ cnt, int* __restrict__ bsums) {
    __shared__ int sm[256];
    int b = blockIdx.x, t = threadIdx.x;
    int base = b * 1024 + t * 4;
    int s = 0;
    #pragma unroll
    for (int j = 0; j < 4; ++j) { int i = base + j; if (i < NN) s += cnt[i]; }
    sm[t] = s; __syncthreads();
    for (int off = 128; off > 0; off >>= 1) {
        if (t < off) sm[t] += sm[t + off];
        __syncthreads();
    }
    if (t == 0) bsums[b] = sm[0];
}

// scan2: exclusive scan of the NB chunk sums (in place)
__global__ __launch_bounds__(128) void scan2(int* __restrict__ bsums) {
    __shared__ int sm[128];
    int t = threadIdx.x;
    int v = (t < NB) ? bsums[t] : 0;
    sm[t] = v; __syncthreads();
    for (int off = 1; off < 128; off <<= 1) {
        int u = (t >= off) ? sm[t - off] : 0;
        __syncthreads(); sm[t] += u; __syncthreads();
    }
    if (t < NB) bsums[t] = sm[t] - v;
}

// scan3: local exclusive scan + chunk base -> offs[] and cursor pos[]
__global__ __launch_bounds__(256) void scan3(const int* __restrict__ cnt, const int* __restrict__ bsums,
                                             int* __restrict__ offs, int* __restrict__ pos) {
    __shared__ int sm[256];
    int b = blockIdx.x, t = threadIdx.x;
    int base = b * 1024 + t * 4;
    int v[4]; int s = 0;
    #pragma unroll
    for (int j = 0; j < 4; ++j) { int i = base + j; v[j] = (i < NN) ? cnt[i] : 0; s += v[j]; }
    sm[t] = s; __syncthreads();
    for (int off = 1; off < 256; off <<= 1) {
        int u = (t >= off) ? sm[t - off] : 0;
        __syncthreads(); sm[t] += u; __syncthreads();
    }
    int run = bsums[b] + (t ? sm[t - 1] : 0);
    #pragma unroll
    for (int j = 0; j < 4; ++j) {
        int i = base + j;
        if (i < NN) {
            offs[i] = run; pos[i] = run; run += v[j];
            if (i == NN - 1) offs[NN] = run;
        }
    }
}

// Scatter edges (packed 4B) into row-sorted order. grid.y = slice of 25000 rows.
__global__ void build_sorted(const int* __restrict__ rows, const int* __restrict__ cols,
                             const float* __restrict__ vals, int* __restrict__ pos,
                             unsigned* __restrict__ edges, int n) {
    int i = blockIdx.x * blockDim.x + threadIdx.x;
    int lo = blockIdx.y * SLICE_ROWS;
    if (i < n) {
        int r = rows[i];
        if (r >= lo && r < lo + SLICE_ROWS) {
            int p = atomicAdd(&pos[r], 1);
            unsigned hb = (unsigned)__half_as_ushort(__float2half(vals[i]));
            edges[p] = (hb << 17) | (unsigned)cols[i];
        }
    }
}

// ---------------- W transpose+convert: Wt[n][k] = bf16(W[k][n]) ----------------

__global__ void wt_kernel(const float* __restrict__ W, __hip_bfloat16* __restrict__ Wt,
                          int K, int N) {
    int i = blockIdx.x * blockDim.x + threadIdx.x;
    if (i < K * N) {
        int n = i / K, k = i - n * K;
        Wt[i] = __float2bfloat16(W[(size_t)k * N + n]);
    }
}

// ---------------- bf16 MFMA GEMM: C[M,N] = A[M,K] @ Bt[N,K]^T ----------------
// [UNCHANGED — byte-identical for clean attribution]

template<int K, int N, bool A_FP32>
__global__ __launch_bounds__(256) void gemm_mfma(const void* __restrict__ Ap,
                                                 const __hip_bfloat16* __restrict__ Bt,
                                                 __hip_bfloat16* __restrict__ C) {
    __shared__ __hip_bfloat16 As[128][40];
    __shared__ __hip_bfloat16 Bs[128][40];
    const int tid  = threadIdx.x;
    const int m0   = blockIdx.y * 128;
    const int n0   = blockIdx.x * 128;
    const int lane = tid & 63;
    const int wave = tid >> 6;
    const int wr   = (wave >> 1) * 64;      // wave row offset in tile
    const int wc   = (wave & 1) * 64;       // wave col offset in tile
    const int srow = tid >> 1;              // staging row 0..127
    const int sk   = (tid & 1) * 16;        // staging k-offset (16 bf16)
    const int lm   = lane & 15;
    const int lk   = (lane >> 4) * 8;       // fragment k-offset

    f32x4 acc[4][4] = {};
    int am = m0 + srow; if (am >= NN) am = NN - 1;   // clamp; C-store guarded
    const int bn = n0 + srow;

    for (int k0 = 0; k0 < K; k0 += 32) {
        // ---- stage A tile [128][32] ----
        if (A_FP32) {
            const float* Ar = (const float*)Ap + (size_t)am * K + k0 + sk;
            float4 f0 = ((const float4*)Ar)[0];
            float4 f1 = ((const float4*)Ar)[1];
            float4 f2 = ((const float4*)Ar)[2];
            float4 f3 = ((const float4*)Ar)[3];
            union { short8 v; __hip_bfloat16 e[8]; } u0, u1;
            u0.e[0] = __float2bfloat16(f0.x); u0.e[1] = __float2bfloat16(f0.y);
            u0.e[2] = __float2bfloat16(f0.z); u0.e[3] = __float2bfloat16(f0.w);
            u0.e[4] = __float2bfloat16(f1.x); u0.e[5] = __float2bfloat16(f1.y);
            u0.e[6] = __float2bfloat16(f1.z); u0.e[7] = __float2bfloat16(f1.w);
            u1.e[0] = __float2bfloat16(f2.x); u1.e[1] = __float2bfloat16(f2.y);
            u1.e[2] = __float2bfloat16(f2.z); u1.e[3] = __float2bfloat16(f2.w);
            u1.e[4] = __float2bfloat16(f3.x); u1.e[5] = __float2bfloat16(f3.y);
            u1.e[6] = __float2bfloat16(f3.z); u1.e[7] = __float2bfloat16(f3.w);
            *(short8*)&As[srow][sk]     = u0.v;
            *(short8*)&As[srow][sk + 8] = u1.v;
        } else {
            const __hip_bfloat16* Ar = (const __hip_bfloat16*)Ap + (size_t)am * K + k0 + sk;
            *(short8*)&As[srow][sk]     = ((const short8*)Ar)[0];
            *(short8*)&As[srow][sk + 8] = ((const short8*)Ar)[1];
        }
        // ---- stage B tile [128][32] from Bt[N][K] ----
        if (bn < N) {
            const __hip_bfloat16* Br = Bt + (size_t)bn * K + k0 + sk;
            *(short8*)&Bs[srow][sk]     = ((const short8*)Br)[0];
            *(short8*)&Bs[srow][sk + 8] = ((const short8*)Br)[1];
        } else {
            short8 z = {};
            *(short8*)&Bs[srow][sk]     = z;
            *(short8*)&Bs[srow][sk + 8] = z;
        }
        __syncthreads();

        short8 af[4], bfr[4];
        #pragma unroll
        for (int q = 0; q < 4; ++q)
            af[q] = *(const short8*)&As[wr + q * 16 + lm][lk];
        #pragma unroll
        for (int r = 0; r < 4; ++r)
            bfr[r] = *(const short8*)&Bs[wc + r * 16 + lm][lk];
        #pragma unroll
        for (int q = 0; q < 4; ++q)
            #pragma unroll
            for (int r = 0; r < 4; ++r)
                acc[q][r] = __builtin_amdgcn_mfma_f32_16x16x32_bf16(af[q], bfr[r], acc[q][r], 0, 0, 0);
        __syncthreads();
    }

    // ---- epilogue: C/D layout col=lane&15, row=(lane>>4)*4+j ----
    #pragma unroll
    for (int q = 0; q < 4; ++q) {
        #pragma unroll
        for (int r = 0; r < 4; ++r) {
            #pragma unroll
            for (int j = 0; j < 4; ++j) {
                int m = m0 + wr + q * 16 + (lane >> 4) * 4 + j;
                int n = n0 + wc + r * 16 + lm;
                if (m < NN && n < N)
                    C[(size_t)m * N + n] = __float2bfloat16(acc[q][r][j]);
            }
        }
    }
}

// ---------------- SpMM, F=256: wave-per-row, batched packed edges ----------------
// Wave loads 64 packed edges coalesced, broadcasts via one readlane each,
// gathers u16x4 (8B/lane). Unroll-8 -> 8 gathers in flight per wave
// (discriminating experiment: latency-bound => ~1.5x; BW-bound => flat).

#define GATHER1(P, A0, A1, A2, A3)                                              \
    {                                                                           \
        u16x4 gv = *(const u16x4*)(gp + (size_t)pcol(P) * 256 + lane * 4);      \
        float vv = pval(P);                                                     \
        A0 = fmaf(vv, bf2f(gv.x), A0); A1 = fmaf(vv, bf2f(gv.y), A1);           \
        A2 = fmaf(vv, bf2f(gv.z), A2); A3 = fmaf(vv, bf2f(gv.w), A3);           \
    }

template<int MODE>
__global__ __launch_bounds__(256) void spmm256_kernel(const int* __restrict__ offs,
                                                      const unsigned* __restrict__ edges,
                                                      const __hip_bfloat16* __restrict__ g,
                                                      __hip_bfloat16* __restrict__ h) {
    const int wid  = threadIdx.x >> 6;
    const int lane = threadIdx.x & 63;
    const int r = blockIdx.x * 4 + wid;
    if (r >= NN) return;
    const int e0 = offs[r], e1 = offs[r + 1];
    const unsigned short* gp = (const unsigned short*)g;
    float a0 = 0.f, a1 = 0.f, a2 = 0.f, a3 = 0.f;

    for (int base = e0; base < e1; base += 64) {
        int ei = base + lane;
        unsigned my = (ei < e1) ? edges[ei] : 0u;
        int cnt = min(64, e1 - base);
        int j = 0;
        for (; j + 7 < cnt; j += 8) {
            unsigned p0 = (unsigned)__builtin_amdgcn_readlane((int)my, j);
            unsigned p1 = (unsigned)__builtin_amdgcn_readlane((int)my, j + 1);
            unsigned p2 = (unsigned)__builtin_amdgcn_readlane((int)my, j + 2);
            unsigned p3 = (unsigned)__builtin_amdgcn_readlane((int)my, j + 3);
            unsigned p4 = (unsigned)__builtin_amdgcn_readlane((int)my, j + 4);
            unsigned p5 = (unsigned)__builtin_amdgcn_readlane((int)my, j + 5);
            unsigned p6 = (unsigned)__builtin_amdgcn_readlane((int)my, j + 6);
            unsigned p7 = (unsigned)__builtin_amdgcn_readlane((int)my, j + 7);
            u16x4 g0 = *(const u16x4*)(gp + (size_t)pcol(p0) * 256 + lane * 4);
            u16x4 g1 = *(const u16x4*)(gp + (size_t)pcol(p1) * 256 + lane * 4);
            u16x4 g2 = *(const u16x4*)(gp + (size_t)pcol(p2) * 256 + lane * 4);
            u16x4 g3 = *(const u16x4*)(gp + (size_t)pcol(p3) * 256 + lane * 4);
            u16x4 g4 = *(const u16x4*)(gp + (size_t)pcol(p4) * 256 + lane * 4);
            u16x4 g5 = *(const u16x4*)(gp + (size_t)pcol(p5) * 256 + lane * 4);
            u16x4 g6 = *(const u16x4*)(gp + (size_t)pcol(p6) * 256 + lane * 4);
            u16x4 g7 = *(const u16x4*)(gp + (size_t)pcol(p7) * 256 + lane * 4);
            float v0 = pval(p0), v1 = pval(p1), v2 = pval(p2), v3 = pval(p3);
            float v4 = pval(p4), v5 = pval(p5), v6 = pval(p6), v7 = pval(p7);
            a0 = fmaf(v0, bf2f(g0.x), a0); a1 = fmaf(v0, bf2f(g0.y), a1);
            a2 = fmaf(v0, bf2f(g0.z), a2); a3 = fmaf(v0, bf2f(g0.w), a3);
            a0 = fmaf(v1, bf2f(g1.x), a0); a1 = fmaf(v1, bf2f(g1.y), a1);
            a2 = fmaf(v1, bf2f(g1.z), a2); a3 = fmaf(v1, bf2f(g1.w), a3);
            a0 = fmaf(v2, bf2f(g2.x), a0); a1 = fmaf(v2, bf2f(g2.y), a1);
            a2 = fmaf(v2, bf2f(g2.z), a2); a3 = fmaf(v2, bf2f(g2.w), a3);
            a0 = fmaf(v3, bf2f(g3.x), a0); a1 = fmaf(v3, bf2f(g3.y), a1);
            a2 = fmaf(v3, bf2f(g3.z), a2); a3 = fmaf(v3, bf2f(g3.w), a3);
            a0 = fmaf(v4, bf2f(g4.x), a0); a1 = fmaf(v4, bf2f(g4.y), a1);
            a2 = fmaf(v4, bf2f(g4.z), a2); a3 = fmaf(v4, bf2f(g4.w), a3);
            a0 = fmaf(v5, bf2f(g5.x), a0); a1 = fmaf(v5, bf2f(g5.y), a1);
            a2 = fmaf(v5, bf2f(g5.z), a2); a3 = fmaf(v5, bf2f(g5.w), a3);
            a0 = fmaf(v6, bf2f(g6.x), a0); a1 = fmaf(v6, bf2f(g6.y), a1);
            a2 = fmaf(v6, bf2f(g6.z), a2); a3 = fmaf(v6, bf2f(g6.w), a3);
            a0 = fmaf(v7, bf2f(g7.x), a0); a1 = fmaf(v7, bf2f(g7.y), a1);
            a2 = fmaf(v7, bf2f(g7.z), a2); a3 = fmaf(v7, bf2f(g7.w), a3);
        }
        for (; j + 3 < cnt; j += 4) {
            unsigned p0 = (unsigned)__builtin_amdgcn_readlane((int)my, j);
            unsigned p1 = (unsigned)__builtin_amdgcn_readlane((int)my, j + 1);
            unsigned p2 = (unsigned)__builtin_amdgcn_readlane((int)my, j + 2);
            unsigned p3 = (unsigned)__builtin_amdgcn_readlane((int)my, j + 3);
            u16x4 g0 = *(const u16x4*)(gp + (size_t)pcol(p0) * 256 + lane * 4);
            u16x4 g1 = *(const u16x4*)(gp + (size_t)pcol(p1) * 256 + lane * 4);
            u16x4 g2 = *(const u16x4*)(gp + (size_t)pcol(p2) * 256 + lane * 4);
            u16x4 g3 = *(const u16x4*)(gp + (size_t)pcol(p3) * 256 + lane * 4);
            float v0 = pval(p0), v1 = pval(p1), v2 = pval(p2), v3 = pval(p3);
            a0 = fmaf(v0, bf2f(g0.x), a0); a1 = fmaf(v0, bf2f(g0.y), a1);
            a2 = fmaf(v0, bf2f(g0.z), a2); a3 = fmaf(v0, bf2f(g0.w), a3);
            a0 = fmaf(v1, bf2f(g1.x), a0); a1 = fmaf(v1, bf2f(g1.y), a1);
            a2 = fmaf(v1, bf2f(g1.z), a2); a3 = fmaf(v1, bf2f(g1.w), a3);
            a0 = fmaf(v2, bf2f(g2.x), a0); a1 = fmaf(v2, bf2f(g2.y), a1);
            a2 = fmaf(v2, bf2f(g2.z), a2); a3 = fmaf(v2, bf2f(g2.w), a3);
            a0 = fmaf(v3, bf2f(g3.x), a0); a1 = fmaf(v3, bf2f(g3.y), a1);
            a2 = fmaf(v3, bf2f(g3.z), a2); a3 = fmaf(v3, bf2f(g3.w), a3);
        }
        for (; j < cnt; ++j) {
            unsigned p0 = (unsigned)__builtin_amdgcn_readlane((int)my, j);
            GATHER1(p0, a0, a1, a2, a3)
        }
    }

    a0 = fmaxf(a0, 0.f); a1 = fmaxf(a1, 0.f);
    a2 = fmaxf(a2, 0.f); a3 = fmaxf(a3, 0.f);
    unsigned short* hp = (unsigned short*)h + (size_t)r * 256 + lane * 4;
    if (MODE == 1) {
        u16x4 hv = *(const u16x4*)hp;
        a0 += bf2f(hv.x); a1 += bf2f(hv.y);
        a2 += bf2f(hv.z); a3 += bf2f(hv.w);
    }
    u16x4 ov;
    ov.x = f2bf(a0); ov.y = f2bf(a1); ov.z = f2bf(a2); ov.w = f2bf(a3);
    *(u16x4*)hp = ov;
}

// ---------------- SpMM, F=40 (final, no relu, fp32 out): wave-per-row, unroll-4 ----------------

__global__ __launch_bounds__(256) void spmm40_kernel(const int* __restrict__ offs,
                                                     const unsigned* __restrict__ edges,
                                                     const __hip_bfloat16* __restrict__ g,
                                                     float* __restrict__ out) {
    const int wid  = threadIdx.x >> 6;
    const int lane = threadIdx.x & 63;
    const int r = blockIdx.x * 4 + wid;
    if (r >= NN) return;
    const int e0 = offs[r], e1 = offs[r + 1];
    const unsigned short* gp = (const unsigned short*)g;
    float acc = 0.f;

    for (int base = e0; base < e1; base += 64) {
        int ei = base + lane;
        unsigned my = (ei < e1) ? edges[ei] : 0u;
        int cnt = min(64, e1 - base);
        int j = 0;
        for (; j + 3 < cnt; j += 4) {
            unsigned p0 = (unsigned)__builtin_amdgcn_readlane((int)my, j);
            unsigned p1 = (unsigned)__builtin_amdgcn_readlane((int)my, j + 1);
            unsigned p2 = (unsigned)__builtin_amdgcn_readlane((int)my, j + 2);
            unsigned p3 = (unsigned)__builtin_amdgcn_readlane((int)my, j + 3);
            if (lane < 40) {
                unsigned short u0 = gp[(size_t)pcol(p0) * 40 + lane];
                unsigned short u1 = gp[(size_t)pcol(p1) * 40 + lane];
                unsigned short u2 = gp[(size_t)pcol(p2) * 40 + lane];
                unsigned short u3 = gp[(size_t)pcol(p3) * 40 + lane];
                acc = fmaf(pval(p0), bf2f(u0), acc);
                acc = fmaf(pval(p1), bf2f(u1), acc);
                acc = fmaf(pval(p2), bf2f(u2), acc);
                acc = fmaf(pval(p3), bf2f(u3), acc);
            }
        }
        for (; j < cnt; ++j) {
            unsigned p0 = (unsigned)__builtin_amdgcn_readlane((int)my, j);
            if (lane < 40) {
                unsigned short u0 = gp[(size_t)pcol(p0) * 40 + lane];
                acc = fmaf(pval(p0), bf2f(u0), acc);
            }
        }
    }
    if (lane < 40) out[(size_t)r * 40 + lane] = acc;
}

// ---------------- launch ----------------

extern "C" void kernel_launch(void* const* d_in, const int* in_sizes, int n_in,
                              void* d_out, int out_size, void* d_ws, size_t ws_size,
                              hipStream_t stream) {
    const float* x     = (const float*)d_in[0];
    const int*   erows = (const int*)d_in[1];
    const int*   ecols = (const int*)d_in[2];
    const float* evals = (const float*)d_in[3];
    const float* W_in  = (const float*)d_in[4];
    const float* W_h1  = (const float*)d_in[5];
    const float* W_h2  = (const float*)d_in[6];
    const float* W_out = (const float*)d_in[7];
    float* out = (float*)d_out;
    const int ne = in_sizes[1];

    // workspace carve-out (~118 MB total)
    char* ws = (char*)d_ws;
    size_t woff = 0;
    auto alloc = [&](size_t bytes) -> void* {
        void* p = ws + woff;
        woff += (bytes + 255) & ~(size_t)255;
        return p;
    };
    int*      cnt   = (int*)alloc(NN * sizeof(int));
    int*      pos   = (int*)alloc(NN * sizeof(int));
    int*      bsums = (int*)alloc(128 * sizeof(int));
    int*      offs  = (int*)alloc((NN + 1) * sizeof(int));
    unsigned* edges = (unsigned*)alloc((size_t)ne * sizeof(unsigned));
    __hip_bfloat16* g  = (__hip_bfloat16*)alloc((size_t)NN * 256 * 2);  // gemm out / gather src
    __hip_bfloat16* h  = (__hip_bfloat16*)alloc((size_t)NN * 256 * 2);  // hidden state
    __hip_bfloat16* Wt_in  = (__hip_bfloat16*)alloc(256 * 512 * 2);     // [N][K]
    __hip_bfloat16* Wt_h1  = (__hip_bfloat16*)alloc(256 * 256 * 2);
    __hip_bfloat16* Wt_h2  = (__hip_bfloat16*)alloc(256 * 256 * 2);
    __hip_bfloat16* Wt_out = (__hip_bfloat16*)alloc(40 * 256 * 2);

    // CSR build (rebuilt each launch; graph shared by all 4 spmms)
    hipMemsetAsync(cnt, 0, NN * sizeof(int), stream);
    int nb = (ne + 255) / 256;
    count_kernel<<<nb, 256, 0, stream>>>(erows, cnt, ne);
    scan1<<<NB, 256, 0, stream>>>(cnt, bsums);
    scan2<<<1, 128, 0, stream>>>(bsums);
    scan3<<<NB, 256, 0, stream>>>(cnt, bsums, offs, pos);
    build_sorted<<<dim3(nb, NSLICE), 256, 0, stream>>>(erows, ecols, evals, pos, edges, ne);

    // weight transposes (tiny)
    wt_kernel<<<(512 * 256 + 255) / 256, 256, 0, stream>>>(W_in,  Wt_in,  512, 256);
    wt_kernel<<<(256 * 256 + 255) / 256, 256, 0, stream>>>(W_h1,  Wt_h1,  256, 256);
    wt_kernel<<<(256 * 256 + 255) / 256, 256, 0, stream>>>(W_h2,  Wt_h2,  256, 256);
    wt_kernel<<<(256 * 40  + 255) / 256, 256, 0, stream>>>(W_out, Wt_out, 256, 40);

    const int mt = (NN + 127) / 128;           // 782 m-tiles
    dim3 g256(2, mt), g40(1, mt);
    const int sb = (NN + 3) / 4;               // spmm blocks (4 rows per block)

    // layer 1: h = relu(spmm(x @ W_in))
    gemm_mfma<512, 256, true ><<<g256, 256, 0, stream>>>(x, Wt_in, g);
    spmm256_kernel<0><<<sb, 256, 0, stream>>>(offs, edges, g, h);
    // layer 2: h = relu(spmm(h @ W_h1)) + h
    gemm_mfma<256, 256, false><<<g256, 256, 0, stream>>>(h, Wt_h1, g);
    spmm256_kernel<1><<<sb, 256, 0, stream>>>(offs, edges, g, h);
    // layer 3: h = relu(spmm(h @ W_h2)) + h
    gemm_mfma<256, 256, false><<<g256, 256, 0, stream>>>(h, Wt_h2, g);
    spmm256_kernel<1><<<sb, 256, 0, stream>>>(offs, edges, g, h);
    // output: logits = spmm(h @ W_out)
    gemm_mfma<256, 40, false><<<g40, 256, 0, stream>>>(h, Wt_out, g);  // g as [NN][40]
    spmm40_kernel<<<sb, 256, 0, stream>>>(offs, edges, g, out);
}